// Round 11
// baseline (22.430 us; speedup 1.0000x reference)
//
#include <hip/hip_runtime.h>

// MakeCutouts: 32 random crops (sz in [224,511]) of a [2,3,512,512] fp32
// image, each adaptive-avg-pooled (PyTorch semantics) to 224x224.
// Output: [32*2, 3, 224, 224] fp32.
//
// R10: every R4-R9 variant kept {load -> __syncthreads -> LDS-read} and all
// landed ~21us =~ 28 blocks/CU x ~750ns serial critical path: the barrier
// couples all waves to the slowest load chain and defeats inter-block
// overlap. This round: WAVE owns an output row end-to-end with a private
// 12KB LDS slice and NO barrier anywhere (in-wave LDS RAW needs only
// lgkmcnt, compiler-inserted). 4 waves/block = 4 consecutive rows,
// grid (56,32), 48KB LDS -> 3 blocks/CU = 12 fully independent waves/CU.
//  - lane owns window cols [8l,8l+8): 2xfloat4 per plane, dy-loop uniform.
//  - plane-5 OOB clamp per-float4 (4-granular; 8-granular clamping would
//    corrupt needed cols when sz>=502 - mod-4 alignment argument).
//  - phase 2: lane emits cols {l, l+64, l+128} (+192+l for l<32), 4
//    predicated taps (dx in 1..4) at window offset +shift; taps <= sz+shift-1
//    <= 511 stay in-slice.

constexpr int CUT   = 224;
constexpr int BC    = 6;          // B*C = 2*3
constexpr int HH    = 512;
constexpr int WW    = 512;
constexpr int PIX   = CUT * CUT;  // 50176
constexpr int PLANE = HH * WW;

__device__ __forceinline__ void f4add(float4& a, const float4 b) {
    a.x += b.x; a.y += b.y; a.z += b.z; a.w += b.w;
}

__global__ __launch_bounds__(256) void cutout_kernel(
    const float* __restrict__ in,     // [6, 512, 512] planes
    const int*   __restrict__ sizes,  // [32]
    const int*   __restrict__ offx,   // [32]
    const int*   __restrict__ offy,   // [32]
    float*       __restrict__ out)    // [32, 6, 224, 224] flat
{
    __shared__ float vs[4][BC][WW];   // 48 KB; wave-private 12 KB slices

    const int t = threadIdx.x;
    const int w = t >> 6;             // wave id -> row within group
    const int l = t & 63;             // lane
    const int n = blockIdx.y;         // cutout (uniform)
    const int i = blockIdx.x * 4 + w; // output row (wave-uniform)

    const int sz = sizes[n];          // uniform -> scalar
    const int oy = offy[n];
    const int ox = offx[n];

    const int sy = (i * sz) / CUT;                        // wave-uniform
    const int dy = ((i + 1) * sz + CUT - 1) / CUT - sy;   // 1..4

    const int ox4   = ox & ~3;        // float4-aligned window start
    const int shift = ox - ox4;       // 0..3
    const int wc    = ox4 + 8 * l;    // this lane's window col (x8)

    // Phase 1: vertical sums over dy rows, 8 cols/lane, 6 planes.
    float4 aA[BC], aB[BC];
    #pragma unroll
    for (int p = 0; p < BC; ++p) {
        aA[p] = float4{0.f, 0.f, 0.f, 0.f};
        aB[p] = float4{0.f, 0.f, 0.f, 0.f};
    }

    int row = (oy + sy) * WW;
    for (int r = 0; r < dy; ++r, row += WW) {   // uniform trip count
        const int idx = row + wc;
        #pragma unroll
        for (int p = 0; p < 5; ++p) {           // planes 0-4: spill past row
            f4add(aA[p], *(const float4*)(in + p * PLANE + idx));      // end lands
            f4add(aB[p], *(const float4*)(in + p * PLANE + idx + 4));  // in unread cols
        }
        const int iA = min(idx,     PLANE - 4); // plane 5: stay in buffer;
        const int iB = min(idx + 4, PLANE - 4); // 4-granular clamp only ever
        f4add(aA[5], *(const float4*)(in + 5 * PLANE + iA));  // hits unread cols
        f4add(aB[5], *(const float4*)(in + 5 * PLANE + iB));
    }

    float* slice = &vs[w][0][0];
    #pragma unroll
    for (int p = 0; p < BC; ++p) {
        *(float4*)(slice + p * WW + 8 * l)     = aA[p];
        *(float4*)(slice + p * WW + 8 * l + 4) = aB[p];
    }
    // No barrier: wave reads only its own slice; lgkmcnt orders write->read.

    // Phase 2: this wave emits its whole output row.
    const size_t obase = (size_t)n * BC * PIX + (size_t)i * CUT;
    #pragma unroll
    for (int rep = 0; rep < 4; ++rep) {
        const int j = rep * 64 + l;
        if (rep == 3 && l >= 32) break;         // 224 = 3.5 waves of cols
        const int sx = (j * sz) / CUT;
        const int dx = ((j + 1) * sz + CUT - 1) / CUT - sx;   // 1..4
        const int x0 = sx + shift;
        const int x1 = x0 + (dx > 1);
        const int x2 = x1 + (dx > 2);
        const int x3 = x2 + (dx > 3);
        const float w1 = dx > 1 ? 1.f : 0.f;
        const float w2 = dx > 2 ? 1.f : 0.f;
        const float w3 = dx > 3 ? 1.f : 0.f;
        const float rr = __builtin_amdgcn_rcpf((float)(dy * dx));

        float* o = out + obase + j;
        #pragma unroll
        for (int p = 0; p < BC; ++p) {
            const float* v = slice + p * WW;
            const float s = v[x0] + w1 * v[x1] + w2 * v[x2] + w3 * v[x3];
            __builtin_nontemporal_store(s * rr, o + p * PIX);
        }
    }
}

extern "C" void kernel_launch(void* const* d_in, const int* in_sizes, int n_in,
                              void* d_out, int out_size, void* d_ws, size_t ws_size,
                              hipStream_t stream) {
    const float* in    = (const float*)d_in[0];
    const int*   sizes = (const int*)d_in[1];
    const int*   offx  = (const int*)d_in[2];
    const int*   offy  = (const int*)d_in[3];
    float*       out   = (float*)d_out;

    cutout_kernel<<<dim3(CUT / 4, 32), dim3(256), 0, stream>>>(
        in, sizes, offx, offy, out);
}